// Round 9
// baseline (182.385 us; speedup 1.0000x reference)
//
#include <hip/hip_runtime.h>
#include <hip/hip_fp16.h>

// GCN 2-layer, N=100000, F=64, H=128, O=100, out [N,1] fp32.
// out = agg(relu(agg(x)@W1 + b1) . (W2@Wl)) + (b2@Wl + bl)
// r9: partB sort key (tile<<6)|dl — consecutive edges have consecutive dl, so
// fused1's ds_add banks (13dl+9col+j)&31 spread uniformly (r8 measured 6.38M
// conflict cycles with random dl; stride tricks can't fix a random scatter).
// Single-variable probe: LDS-pipe-bound -> fused1 drops; fill-bound -> flat.
//  memset: bcur[1563] = 0.
//  partA:  blocks [0,nchunks): LDS multi-split of 4096 edges into padded
//          dst-buckets (ONE reserve-atomic per bucket per block, staged
//          run-length writes); two-level scan (local-8 + 256 Hillis).
//          blocks [nchunks,+9): prep (W1 fp16 hi+lo, v=W2@Wl, c, zero y-row).
//  partB:  per bucket: 832-bin (tile,dl) counting sort; deg/dinv from bin
//          sums; emits int16 (2^12) dinv-prescaled y.
//  fused1: 1563 blocks (~6/CU, 19.7KB LDS, occ ~48%); tile-order gather keeps
//          live y-tile L2-hot per XCD; 8-edge x 8-col gather, 1-deep csr
//          prefetch; invalid slots read zero-row y[N]; int16 sext -> native
//          ds_add_u32 into stride-77 acci. MFMA + fused L2-weight epilogue.
//  out:    per-bucket tile-major zz gather + native int LDS accumulate
//          (sorted dl -> conflict-light).
// fp32 LDS atomicAdd is a ~440cyc CAS loop on this toolchain (r1-r3);
// everything accumulates in int fixed-point (native ds_add_u32).

#define N_NODES 100000
#define F_IN 64
#define HID 128
#define OUT2 100
#define BSHIFT 6
#define BNODES 64
#define NBUCKETS ((N_NODES + BNODES - 1) / BNODES)  // 1563
#define SCAP 1408   // bucket capacity: mean 1024 + 12 sigma (sigma=32)
#define ACHUNK 4096 // edges per partA block
#define NB_PAD 2048
#define SENTB 0xFFFFu
#define SENTE 0xFFFFFFFFu
#define TSHIFT 13   // src tile = src >> 13 (8192 srcs = 1 MB of y per tile)
#define NTILES 13   // ceil(100000 / 8192)
#define NKEY_PAD 1024  // (tile<<6)|dl keys: 13*64=832, padded
#define RSTRIDE 77  // acci ints per node row: 13*dl mod 32 full-period
#define ZROW N_NODES          // zero y-row for invalid gather slots
#define YSCALE 4096.0f        // y int16 fixed-point 2^12
#define YINV   (1.0f / 4096.0f)
#define ZSCALE 8192.0f        // zz accumulation fixed-point 2^13
#define ZINV   (1.0f / 8192.0f)

typedef _Float16 half8 __attribute__((ext_vector_type(8)));
typedef float f32x4 __attribute__((ext_vector_type(4)));

static __device__ __forceinline__ half8 as_half8(uint4 u) {
    union { uint4 u; half8 h; } x; x.u = u; return x.h;
}

// Pass A (+prep): edge blocks LDS-multisplit into padded dst-buckets;
// prep blocks pack W1 / v / c / zero-row. bcur = per-bucket COUNTS
// (memset 0 before launch); reserve = b*SCAP + atomicAdd(count).
__global__ __launch_bounds__(256) void partA_kernel(
    const int* __restrict__ src, const int* __restrict__ dst,
    int* __restrict__ bcur, unsigned int* __restrict__ ebuf, int E, int nchunks,
    const float* __restrict__ W1, const float* __restrict__ W2,
    const float* __restrict__ b2, const float* __restrict__ Wl,
    const float* __restrict__ bl,
    float* __restrict__ v, float* __restrict__ c, uint4* __restrict__ Wpk,
    int* __restrict__ yzero) {
    int t = threadIdx.x;
    if ((int)blockIdx.x >= nchunks) {
        int pb = (int)blockIdx.x - nchunks;
        if (pb < 8) {
            // idx: bit10 = part (0=hi,1=lo), bits9..7 = cb, bit6 = kf, bits5..0 = lane
            int idx = pb * 256 + t;
            int lane2 = idx & 63;
            int kf    = (idx >> 6) & 1;
            int cb    = (idx >> 7) & 7;
            int part  = (idx >> 10) & 1;
            union { uint4 u; unsigned short s[8]; } pk;
            #pragma unroll
            for (int j = 0; j < 8; ++j) {
                int k    = kf * 32 + (lane2 >> 4) * 8 + j;
                int colg = cb * 16 + (lane2 & 15);
                float w = W1[k * HID + colg];
                __half h = __float2half_rn(w);
                if (part) h = __float2half_rn(w - __half2float(h));
                pk.s[j] = __half_as_ushort(h);
            }
            Wpk[idx] = pk.u;
        } else {
            if (t < HID) {
                float acc = 0.f;
                for (int k = 0; k < OUT2; ++k) acc += W2[t * OUT2 + k] * Wl[k];
                v[t] = acc;
            } else if (t == HID) {
                float acc = bl[0];
                for (int k = 0; k < OUT2; ++k) acc += b2[k] * Wl[k];
                *c = acc;
            }
            if (t < 128) yzero[t] = 0;   // zero rows (int16) at y[N..]
        }
        return;
    }
    __shared__ unsigned int stage[ACHUNK];       // 16 KB
    __shared__ unsigned short sb[ACHUNK];        // 8 KB
    __shared__ int hist[NB_PAD];                 // 8 KB each
    __shared__ int ocnt[NB_PAD];
    __shared__ int gbase[NB_PAD];
    __shared__ int cnt2[NB_PAD];
    __shared__ int tsum[256];
    int base = blockIdx.x * ACHUNK;
    int total = E - base; if (total > ACHUNK) total = ACHUNK;

    #pragma unroll
    for (int i = 0; i < 8; ++i) { hist[t + i * 256] = 0; cnt2[t + i * 256] = 0; }
    __syncthreads();

    unsigned int pe[16];
    unsigned short bk[16];
    #pragma unroll
    for (int k = 0; k < 16; ++k) {
        int e = base + k * 256 + t;
        if (e < E) {
            int s = src[e], d = dst[e];
            pe[k] = ((unsigned int)s << BSHIFT) | (unsigned int)(d & (BNODES - 1));
            bk[k] = (unsigned short)(d >> BSHIFT);
            atomicAdd(&hist[bk[k]], 1);
        } else {
            bk[k] = SENTB;
        }
    }
    __syncthreads();
    #pragma unroll
    for (int i = 0; i < 8; ++i) ocnt[t + i * 256] = hist[t + i * 256];
    __syncthreads();
    // two-level inclusive scan of hist[0..2047]: thread owns bins [8t,8t+8)
    int lcl[8];
    int s = 0;
    #pragma unroll
    for (int i = 0; i < 8; ++i) { s += hist[8 * t + i]; lcl[i] = s; }
    tsum[t] = s;
    __syncthreads();
    for (int off = 1; off < 256; off <<= 1) {
        int vv = (t >= off) ? tsum[t - off] : 0;
        __syncthreads();
        tsum[t] += vv;
        __syncthreads();
    }
    int cbase = tsum[t] - s;   // exclusive across chunks
    #pragma unroll
    for (int i = 0; i < 8; ++i) hist[8 * t + i] = cbase + lcl[i];  // inclusive
    __syncthreads();
    #pragma unroll
    for (int i = 0; i < 8; ++i) {
        int b = (t + i * 256 + blockIdx.x * 131) & (NB_PAD - 1);
        int cc = ocnt[b];
        if (cc > 0 && b < NBUCKETS)
            gbase[b] = b * SCAP + atomicAdd(&bcur[b], cc);
    }
    __syncthreads();
    #pragma unroll
    for (int k = 0; k < 16; ++k) {
        if (bk[k] != SENTB) {
            int b = bk[k];
            int pos = (hist[b] - ocnt[b]) + atomicAdd(&cnt2[b], 1);
            stage[pos] = pe[k];
            sb[pos] = (unsigned short)b;
        }
    }
    __syncthreads();
    #pragma unroll
    for (int k = 0; k < 16; ++k) {
        int idx = k * 256 + t;
        if (idx < total) {
            int b = sb[idx];
            int lo = hist[b] - ocnt[b];
            ebuf[gbase[b] + (idx - lo)] = stage[idx];
        }
    }
}

// Pass B: per bucket: 832-bin (tile<<6|dl) counting sort (in-place, full
// entries src<<6|dl); deg/dinv from per-dl bin sums; emits int16 (2^12)
// pre-scaled y rows.
__global__ __launch_bounds__(256) void partB_kernel(
    const int* __restrict__ bcur, unsigned int* __restrict__ csr,
    float* __restrict__ dinv,
    const float4* __restrict__ x4, uint2* __restrict__ y2, int n) {
    __shared__ int scnt[NKEY_PAD];           // 4 KB counts
    __shared__ int kbase[NKEY_PAD];          // 4 KB scatter cursors
    __shared__ int tsum[256];
    __shared__ float sdinv[BNODES];
    __shared__ unsigned int sbuf[SCAP];      // 5.5 KB
    int b = blockIdx.x, t = threadIdx.x;
    int node0 = b << BSHIFT;
    int nlocal = min(BNODES, n - node0);
    int base = b * SCAP;
    int cnt = bcur[b];
    #pragma unroll
    for (int i = 0; i < 4; ++i) scnt[t + i * 256] = 0;
    __syncthreads();
    unsigned int er[6];
    #pragma unroll
    for (int k = 0; k < 6; ++k) {
        int idx = k * 256 + t;
        er[k] = (idx < cnt) ? csr[base + idx] : SENTE;
        if (er[k] != SENTE) {
            int key = (int)((er[k] >> (BSHIFT + TSHIFT)) << 6) | (int)(er[k] & 63u);
            atomicAdd(&scnt[key], 1);
        }
    }
    __syncthreads();
    // deg/dinv from per-dl sums over tiles
    if (t < BNODES) {
        int deg = 0;
        #pragma unroll
        for (int i = 0; i < NTILES; ++i) deg += scnt[(i << 6) | t];
        float sd = rsqrtf((float)deg + 1.0f);
        sdinv[t] = sd;
        if (t < nlocal) dinv[node0 + t] = sd;
    }
    // two-level exclusive scan of scnt[0..1023]: thread owns keys [4t,4t+4)
    int lcl[4];
    int s = 0;
    #pragma unroll
    for (int i = 0; i < 4; ++i) { lcl[i] = s; s += scnt[4 * t + i]; }
    tsum[t] = s;
    __syncthreads();
    for (int off = 1; off < 256; off <<= 1) {
        int vv = (t >= off) ? tsum[t - off] : 0;
        __syncthreads();
        tsum[t] += vv;
        __syncthreads();
    }
    int cbase = tsum[t] - s;   // exclusive across chunks
    #pragma unroll
    for (int i = 0; i < 4; ++i) kbase[4 * t + i] = cbase + lcl[i];
    __syncthreads();
    // scatter to sbuf in (tile,dl) order
    #pragma unroll
    for (int k = 0; k < 6; ++k) {
        unsigned int e = er[k];
        if (e != SENTE) {
            int key = (int)((e >> (BSHIFT + TSHIFT)) << 6) | (int)(e & 63u);
            int p = atomicAdd(&kbase[key], 1);
            sbuf[p] = e;
        }
    }
    __syncthreads();
    for (int idx = t; idx < cnt; idx += 256) csr[base + idx] = sbuf[idx];
    // y emission: int16 fixed-point, dinv[src]-prescaled
    for (int i = t; i < nlocal * 16; i += 256) {
        int nl = i >> 4;
        int gi = (node0 + nl) * 16 + (i & 15);
        float sc = sdinv[nl] * YSCALE;
        float4 xv = x4[gi];
        int a0 = __float2int_rn(xv.x * sc);
        int a1 = __float2int_rn(xv.y * sc);
        int a2 = __float2int_rn(xv.z * sc);
        int a3 = __float2int_rn(xv.w * sc);
        uint2 pk;
        pk.x = ((unsigned int)a0 & 0xFFFFu) | ((unsigned int)a1 << 16);
        pk.y = ((unsigned int)a2 & 0xFFFFu) | ((unsigned int)a3 << 16);
        y2[gi] = pk;
    }
}

// Fused layer 1: block = bucket (64 dst nodes), 1563 blocks (~6/CU).
// csr is (tile,dl)-sorted -> live 1MB y-tile stays L2-hot per XCD AND the
// 8 edges per gather group have near-consecutive dl -> ds_add banks
// (13dl+9col+j)&31 spread uniformly (conflict fix for random-dl scatter).
#define F1_ISSUE(EE, U, DL)                                            \
    _Pragma("unroll")                                                  \
    for (int g = 0; g < 8; ++g) {                                      \
        unsigned int e_ = __shfl((EE), g * 8 + q, 64);                 \
        int srow_ = (e_ != SENTE) ? (int)(e_ >> BSHIFT) : ZROW;        \
        DL[g] = (int)(e_ & (BNODES - 1));                              \
        U[g] = y4[srow_ * 8 + col];                                    \
    }

#define F1_CONSUME(U, DL)                                              \
    _Pragma("unroll")                                                  \
    for (int g = 0; g < 8; ++g) {                                      \
        int* rowp_ = &acci[DL[g] * RSTRIDE + col * 9];                 \
        const int* up_ = (const int*)&U[g];                            \
        _Pragma("unroll")                                              \
        for (int j = 0; j < 4; ++j) {                                  \
            int d_ = up_[j];                                           \
            atomicAdd(&rowp_[2 * j],     (d_ << 16) >> 16);            \
            atomicAdd(&rowp_[2 * j + 1], d_ >> 16);                    \
        }                                                              \
    }

__global__ __launch_bounds__(256, 6) void fused1_kernel(
    const int4* __restrict__ y4, const short* __restrict__ yh,
    const unsigned int* __restrict__ csr, const int* __restrict__ bcur,
    const float* __restrict__ dinv, const uint4* __restrict__ Wpk,
    const float* __restrict__ b1, const float* __restrict__ v,
    float* __restrict__ zz, int n) {
    __shared__ int acci[BNODES * RSTRIDE];   // 19712 B
    int t = threadIdx.x;
    int lane = t & 63, wave = t >> 6;
    int q = lane >> 3, col = lane & 7;
    int b = blockIdx.x;
    int node0 = b << BSHIFT;
    int nlocal = min(BNODES, n - node0);
    int base = b * SCAP;
    int cnt = bcur[b];

    // self-loop init: acc[r][f] = y[node0+r][f] (int16, already dinv-prescaled)
    for (int r = wave; r < BNODES; r += 4) {
        int vv = 0;
        if (r < nlocal) vv = (int)yh[(node0 + r) * 64 + lane];
        acci[r * RSTRIDE + q * 9 + col] = vv;
    }
    __syncthreads();

    // 1-deep pipelined edge accumulation in (tile,dl) order (waves interleave
    // 64-edge chunks; 256-edge block round).
    int nr = (cnt + 255) >> 8;
    int lpos = wave * 64 + lane;
    unsigned int ee = (lpos < cnt) ? csr[base + lpos] : SENTE;
    for (int r = 0; r < nr; ++r) {
        int pn = lpos + (r + 1) * 256;
        unsigned int een = (pn < cnt) ? csr[base + pn] : SENTE;
        int4 u[8]; int dl[8];
        F1_ISSUE(ee, u, dl);
        F1_CONSUME(u, dl);
        ee = een;
    }
    __syncthreads();

    // MFMA + epilogue: wave handles its one 16-node sub-tile.
    int mm = lane & 15, kq = lane >> 4;
    int st = wave;
    int row = st * 16 + mm;
    float dis = ((row < nlocal) ? dinv[node0 + row] : 0.f) * YINV;
    const int* ap = &acci[row * RSTRIDE];
    half8 A0, A1;
    #pragma unroll
    for (int j = 0; j < 8; ++j) {
        A0[j] = (_Float16)(dis * (float)ap[kq * 9 + j]);
        A1[j] = (_Float16)(dis * (float)ap[(4 + kq) * 9 + j]);
    }
    f32x4 acc[8];
    #pragma unroll
    for (int cb = 0; cb < 8; ++cb) acc[cb] = (f32x4){0.f, 0.f, 0.f, 0.f};
    #pragma unroll
    for (int cb = 0; cb < 8; ++cb) {
        half8 bh0 = as_half8(Wpk[(cb * 2 + 0) * 64 + lane]);
        half8 bh1 = as_half8(Wpk[(cb * 2 + 1) * 64 + lane]);
        half8 bl0 = as_half8(Wpk[1024 + (cb * 2 + 0) * 64 + lane]);
        half8 bl1 = as_half8(Wpk[1024 + (cb * 2 + 1) * 64 + lane]);
        acc[cb] = __builtin_amdgcn_mfma_f32_16x16x32_f16(A0, bh0, acc[cb], 0, 0, 0);
        acc[cb] = __builtin_amdgcn_mfma_f32_16x16x32_f16(A1, bh1, acc[cb], 0, 0, 0);
        acc[cb] = __builtin_amdgcn_mfma_f32_16x16x32_f16(A0, bl0, acc[cb], 0, 0, 0);
        acc[cb] = __builtin_amdgcn_mfma_f32_16x16x32_f16(A1, bl1, acc[cb], 0, 0, 0);
    }
    float zp[4] = {0.f, 0.f, 0.f, 0.f};
    #pragma unroll
    for (int cb = 0; cb < 8; ++cb) {
        int colg = cb * 16 + mm;
        float bb1 = b1[colg], vv = v[colg];
        #pragma unroll
        for (int rr = 0; rr < 4; ++rr) {
            float h = acc[cb][rr] + bb1;
            h = fmaxf(h, 0.f);
            zp[rr] += h * vv;
        }
    }
    #pragma unroll
    for (int off = 1; off < 16; off <<= 1) {
        #pragma unroll
        for (int rr = 0; rr < 4; ++rr) zp[rr] += __shfl_xor(zp[rr], off, 64);
    }
    if (mm == 0) {
        int nb = st * 16 + kq * 4;
        #pragma unroll
        for (int rr = 0; rr < 4; ++rr)
            if (nb + rr < nlocal)
                zz[node0 + nb + rr] = dinv[node0 + nb + rr] * zp[rr];
    }
}

// Layer 2 (collapsed): per-bucket tile-major zz gather (L1/L2 window) +
// native int LDS accumulate (sorted dl -> conflict-light).
// out[i] = c + dinv[i]*(zz[i] + sum_in zz[s]).
__global__ __launch_bounds__(256) void out_kernel(
    const int* __restrict__ bcur, const unsigned int* __restrict__ csr,
    const float* __restrict__ dinv, const float* __restrict__ zz,
    const float* __restrict__ c, float* __restrict__ out, int n) {
    __shared__ int acc2[BNODES];
    int b = blockIdx.x, t = threadIdx.x;
    int node0 = b << BSHIFT;
    int nlocal = min(BNODES, n - node0);
    int base = b * SCAP;
    int cnt = bcur[b];
    if (t < BNODES) acc2[t] = 0;
    __syncthreads();
    for (int idx = t; idx < cnt; idx += 256) {
        unsigned int e = csr[base + idx];
        float z = zz[e >> BSHIFT];
        atomicAdd(&acc2[e & (BNODES - 1)], __float2int_rn(z * ZSCALE));
    }
    __syncthreads();
    if (t < nlocal) {
        int node = node0 + t;
        out[node] = c[0] + dinv[node] * ((float)acc2[t] * ZINV + zz[node]);
    }
}

extern "C" void kernel_launch(void* const* d_in, const int* in_sizes, int n_in,
                              void* d_out, int out_size, void* d_ws, size_t ws_size,
                              hipStream_t stream) {
    const float* x  = (const float*)d_in[0];
    const int*   ei = (const int*)d_in[1];
    const float* W1 = (const float*)d_in[2];
    const float* b1 = (const float*)d_in[3];
    const float* W2 = (const float*)d_in[4];
    const float* b2 = (const float*)d_in[5];
    const float* Wl = (const float*)d_in[6];
    const float* bl = (const float*)d_in[7];
    float* out = (float*)d_out;

    int E = in_sizes[1] / 2;
    const int* src = ei;
    const int* dst = ei + E;

    float* ws      = (float*)d_ws;
    float* dinv    = ws;                        // 100000
    float* zz      = dinv + N_NODES;            // 100000
    float* v       = zz + N_NODES;              // 128
    float* c       = v + HID;                   // 4
    int*   bcur    = (int*)(c + 4);             // 1563 counts (pad to 2048)
    int*   csr     = bcur + NB_PAD;             // NBUCKETS*SCAP = 2200704 ints
    uint4* Wpk     = (uint4*)(csr + (size_t)NBUCKETS * SCAP);  // 2048 uint4
    short* y       = (short*)((float*)Wpk + 8192);  // (N+4)*64 int16

    int nchunks = (E + ACHUNK - 1) / ACHUNK;   // 391

    hipMemsetAsync(bcur, 0, NBUCKETS * sizeof(int), stream);
    partA_kernel<<<nchunks + 9, 256, 0, stream>>>(
        src, dst, bcur, (unsigned int*)csr, E, nchunks,
        W1, W2, b2, Wl, bl, v, c, Wpk, (int*)(y + (size_t)ZROW * 64));
    partB_kernel<<<NBUCKETS, 256, 0, stream>>>(
        bcur, (unsigned int*)csr, dinv, (const float4*)x, (uint2*)y, N_NODES);
    fused1_kernel<<<NBUCKETS, 256, 0, stream>>>(
        (const int4*)y, (const short*)y, (const unsigned int*)csr,
        bcur, dinv, Wpk, b1, v, zz, N_NODES);
    out_kernel<<<NBUCKETS, 256, 0, stream>>>(
        bcur, (const unsigned int*)csr, dinv, zz, c, out, N_NODES);
}

// Round 10
// 176.450 us; speedup vs baseline: 1.0336x; 1.0336x over previous
//
#include <hip/hip_runtime.h>
#include <hip/hip_fp16.h>

// GCN 2-layer, N=100000, F=64, H=128, O=100, out [N,1] fp32.
// out = agg(relu(agg(x)@W1 + b1) . (W2@Wl)) + (b2@Wl + bl)
// r10: BNODES=128 (fetch-optimal: r5 measured 66MB) + FORCED 8-deep gather MLP.
// r5's VGPR=36 proves the compiler serialized the 8-load pipeline (8 int4 = 32
// regs); fill rate was register-allocation-limited (0.51 miss/cyc vs the ~1
// miss/cyc/XCD L2 ceiling r0/r8 both pin). Fix: issue all 8 gathers, then
// sched_barrier(0) so loads can't sink into the consume loop; launch_bounds
// (256,4) = 128-VGPR headroom. Per-round __syncthreads keeps the block's live
// tile window at 256 edges (1.6MB < 4MB XCD L2). r9's (tile,dl) sort REVERTED:
// same-dl groups made same-address LDS atomics (conflicts 6.4M->8.2M).
//  memset: bcur[782] = 0.
//  partA:  blocks [0,nchunks): LDS multi-split into padded dst-buckets (ONE
//          reserve-atomic per bucket per block, staged run-length writes,
//          two-level scan). blocks [nchunks,+9): prep (W1 fp16 hi+lo pack,
//          v=W2@Wl, c=b2.Wl+bl, zero y-row).
//  partB:  per bucket: dl-histogram -> dinv; 13-bin TILE-major counting sort
//          (tile = src>>13 = 1MB of y); emits int16 (2^12) dinv-prescaled y.
//  fused1: 782 blocks, 4/CU LDS cap; tile-order gather; int16 sext -> native
//          ds_add_u32 into stride-72 acci. MFMA + fused L2-weight epilogue.
//  out:    per-bucket tile-major zz gather + native int LDS accumulate.
// fp32 LDS atomicAdd is a ~440cyc CAS loop on this toolchain (r1-r3);
// everything accumulates in int fixed-point (native ds_add_u32).

#define N_NODES 100000
#define F_IN 64
#define HID 128
#define OUT2 100
#define BSHIFT 7
#define BNODES 128
#define NBUCKETS ((N_NODES + BNODES - 1) / BNODES)  // 782
#define SCAP 2560   // bucket capacity: mean 2046 + ~11 sigma
#define ACHUNK 4096 // edges per partA block
#define NB_PAD 1024
#define SENTB 0xFFFFu
#define SENTE 0xFFFFFFFFu
#define TSHIFT 13   // src tile = src >> 13 (8192 srcs = 1 MB of y per tile)
#define NTILES 13   // ceil(100000 / 8192)
#define RSTRIDE 72  // acci ints per node row: 8 cols x 9 (8 data + 1 pad)
#define ZROW N_NODES          // zero y-row for invalid gather slots
#define YSCALE 4096.0f        // y int16 fixed-point 2^12
#define YINV   (1.0f / 4096.0f)
#define ZSCALE 8192.0f        // zz accumulation fixed-point 2^13
#define ZINV   (1.0f / 8192.0f)

typedef _Float16 half8 __attribute__((ext_vector_type(8)));
typedef float f32x4 __attribute__((ext_vector_type(4)));

static __device__ __forceinline__ half8 as_half8(uint4 u) {
    union { uint4 u; half8 h; } x; x.u = u; return x.h;
}

// Pass A (+prep): edge blocks LDS-multisplit into padded dst-buckets;
// prep blocks pack W1 / v / c / zero-row. bcur = per-bucket COUNTS
// (memset 0 before launch); reserve = b*SCAP + atomicAdd(count).
__global__ __launch_bounds__(256) void partA_kernel(
    const int* __restrict__ src, const int* __restrict__ dst,
    int* __restrict__ bcur, unsigned int* __restrict__ ebuf, int E, int nchunks,
    const float* __restrict__ W1, const float* __restrict__ W2,
    const float* __restrict__ b2, const float* __restrict__ Wl,
    const float* __restrict__ bl,
    float* __restrict__ v, float* __restrict__ c, uint4* __restrict__ Wpk,
    int* __restrict__ yzero) {
    int t = threadIdx.x;
    if ((int)blockIdx.x >= nchunks) {
        int pb = (int)blockIdx.x - nchunks;
        if (pb < 8) {
            // idx: bit10 = part (0=hi,1=lo), bits9..7 = cb, bit6 = kf, bits5..0 = lane
            int idx = pb * 256 + t;
            int lane2 = idx & 63;
            int kf    = (idx >> 6) & 1;
            int cb    = (idx >> 7) & 7;
            int part  = (idx >> 10) & 1;
            union { uint4 u; unsigned short s[8]; } pk;
            #pragma unroll
            for (int j = 0; j < 8; ++j) {
                int k    = kf * 32 + (lane2 >> 4) * 8 + j;
                int colg = cb * 16 + (lane2 & 15);
                float w = W1[k * HID + colg];
                __half h = __float2half_rn(w);
                if (part) h = __float2half_rn(w - __half2float(h));
                pk.s[j] = __half_as_ushort(h);
            }
            Wpk[idx] = pk.u;
        } else {
            if (t < HID) {
                float acc = 0.f;
                for (int k = 0; k < OUT2; ++k) acc += W2[t * OUT2 + k] * Wl[k];
                v[t] = acc;
            } else if (t == HID) {
                float acc = bl[0];
                for (int k = 0; k < OUT2; ++k) acc += b2[k] * Wl[k];
                *c = acc;
            }
            if (t < 128) yzero[t] = 0;   // zero rows (int16) at y[N..]
        }
        return;
    }
    __shared__ unsigned int stage[ACHUNK];       // 16 KB
    __shared__ unsigned short sb[ACHUNK];        // 8 KB
    __shared__ int hist[NB_PAD];                 // 4 KB each
    __shared__ int ocnt[NB_PAD];
    __shared__ int gbase[NB_PAD];
    __shared__ int cnt2[NB_PAD];
    __shared__ int tsum[256];
    int base = blockIdx.x * ACHUNK;
    int total = E - base; if (total > ACHUNK) total = ACHUNK;

    #pragma unroll
    for (int i = 0; i < 4; ++i) { hist[t + i * 256] = 0; cnt2[t + i * 256] = 0; }
    __syncthreads();

    unsigned int pe[16];
    unsigned short bk[16];
    #pragma unroll
    for (int k = 0; k < 16; ++k) {
        int e = base + k * 256 + t;
        if (e < E) {
            int s = src[e], d = dst[e];
            pe[k] = ((unsigned int)s << BSHIFT) | (unsigned int)(d & (BNODES - 1));
            bk[k] = (unsigned short)(d >> BSHIFT);
            atomicAdd(&hist[bk[k]], 1);
        } else {
            bk[k] = SENTB;
        }
    }
    __syncthreads();
    #pragma unroll
    for (int i = 0; i < 4; ++i) ocnt[t + i * 256] = hist[t + i * 256];
    __syncthreads();
    // two-level inclusive scan of hist[0..1023]: thread owns bins [4t,4t+4)
    int lcl[4];
    int s = 0;
    #pragma unroll
    for (int i = 0; i < 4; ++i) { s += hist[4 * t + i]; lcl[i] = s; }
    tsum[t] = s;
    __syncthreads();
    for (int off = 1; off < 256; off <<= 1) {
        int vv = (t >= off) ? tsum[t - off] : 0;
        __syncthreads();
        tsum[t] += vv;
        __syncthreads();
    }
    int cbase = tsum[t] - s;   // exclusive across thread chunks
    #pragma unroll
    for (int i = 0; i < 4; ++i) hist[4 * t + i] = cbase + lcl[i];  // inclusive
    __syncthreads();
    #pragma unroll
    for (int i = 0; i < 4; ++i) {
        int b = (t + i * 256 + blockIdx.x * 131) & (NB_PAD - 1);
        int cc = ocnt[b];
        if (cc > 0 && b < NBUCKETS)
            gbase[b] = b * SCAP + atomicAdd(&bcur[b], cc);
    }
    __syncthreads();
    #pragma unroll
    for (int k = 0; k < 16; ++k) {
        if (bk[k] != SENTB) {
            int b = bk[k];
            int pos = (hist[b] - ocnt[b]) + atomicAdd(&cnt2[b], 1);
            stage[pos] = pe[k];
            sb[pos] = (unsigned short)b;
        }
    }
    __syncthreads();
    #pragma unroll
    for (int k = 0; k < 16; ++k) {
        int idx = k * 256 + t;
        if (idx < total) {
            int b = sb[idx];
            int lo = hist[b] - ocnt[b];
            ebuf[gbase[b] + (idx - lo)] = stage[idx];
        }
    }
}

// Pass B: per bucket: dl-histogram -> dinv; 13-bin TILE-major counting sort
// (in-place, full entries src<<7|dl); emits int16 (2^12) pre-scaled y rows.
__global__ __launch_bounds__(256) void partB_kernel(
    const int* __restrict__ bcur, unsigned int* __restrict__ csr,
    float* __restrict__ dinv,
    const float4* __restrict__ x4, uint2* __restrict__ y2, int n) {
    __shared__ int lcnt[BNODES];
    __shared__ float sdinv[BNODES];
    __shared__ int tcnt[16];
    __shared__ int tcur[16];
    __shared__ unsigned int sbuf[SCAP];      // 10 KB
    int b = blockIdx.x, t = threadIdx.x;
    int node0 = b << BSHIFT;
    int nlocal = min(BNODES, n - node0);
    int base = b * SCAP;
    int cnt = bcur[b];
    if (t < BNODES) lcnt[t] = 0;
    if (t < 16) tcnt[t] = 0;
    __syncthreads();
    unsigned int er[SCAP / 256];
    #pragma unroll
    for (int k = 0; k < SCAP / 256; ++k) {
        int idx = k * 256 + t;
        er[k] = (idx < cnt) ? csr[base + idx] : SENTE;
        if (er[k] != SENTE) {
            atomicAdd(&lcnt[er[k] & (BNODES - 1)], 1);
            atomicAdd(&tcnt[er[k] >> (BSHIFT + TSHIFT)], 1);
        }
    }
    __syncthreads();
    if (t < BNODES) {
        float sd = rsqrtf((float)lcnt[t] + 1.0f);
        sdinv[t] = sd;
        if (t < nlocal) dinv[node0 + t] = sd;
    }
    if (t == 0) {
        int s = 0;
        #pragma unroll
        for (int i = 0; i < NTILES; ++i) { tcur[i] = s; s += tcnt[i]; }
    }
    __syncthreads();
    #pragma unroll
    for (int k = 0; k < SCAP / 256; ++k) {
        unsigned int e = er[k];
        if (e != SENTE) {
            int p = atomicAdd(&tcur[e >> (BSHIFT + TSHIFT)], 1);
            sbuf[p] = e;
        }
    }
    __syncthreads();
    for (int idx = t; idx < cnt; idx += 256) csr[base + idx] = sbuf[idx];
    // y emission: int16 fixed-point, dinv[src]-prescaled
    for (int i = t; i < nlocal * 16; i += 256) {
        int nl = i >> 4;
        int gi = (node0 + nl) * 16 + (i & 15);
        float sc = sdinv[nl] * YSCALE;
        float4 xv = x4[gi];
        int a0 = __float2int_rn(xv.x * sc);
        int a1 = __float2int_rn(xv.y * sc);
        int a2 = __float2int_rn(xv.z * sc);
        int a3 = __float2int_rn(xv.w * sc);
        uint2 pk;
        pk.x = ((unsigned int)a0 & 0xFFFFu) | ((unsigned int)a1 << 16);
        pk.y = ((unsigned int)a2 & 0xFFFFu) | ((unsigned int)a3 << 16);
        y2[gi] = pk;
    }
}

// Fused layer 1: block = bucket (128 dst nodes), 782 blocks, 4/CU LDS cap.
// csr is tile-major -> live 1MB y-tile stays L2-hot per XCD.
// Gather: 64 lanes = 8 edges (q=lane>>3) x 8 int4 cols (col=lane&7).
// All 8 gathers ISSUED, then sched_barrier(0), then consumed: true 8-deep MLP
// (r5's VGPR=36 shows the compiler otherwise serializes to ~2-deep).
// Per-round __syncthreads locks waves: block live window = 256 edges = 1.6MB.
#define F1_ISSUE(EE, U, DL)                                            \
    _Pragma("unroll")                                                  \
    for (int g = 0; g < 8; ++g) {                                      \
        unsigned int e_ = __shfl((EE), g * 8 + q, 64);                 \
        int srow_ = (e_ != SENTE) ? (int)(e_ >> BSHIFT) : ZROW;        \
        DL[g] = (int)(e_ & (BNODES - 1));                              \
        U[g] = y4[srow_ * 8 + col];                                    \
    }

#define F1_CONSUME(U, DL)                                              \
    _Pragma("unroll")                                                  \
    for (int g = 0; g < 8; ++g) {                                      \
        int* rowp_ = &acci[DL[g] * RSTRIDE + col * 9];                 \
        const int* up_ = (const int*)&U[g];                            \
        _Pragma("unroll")                                              \
        for (int j = 0; j < 4; ++j) {                                  \
            int d_ = up_[j];                                           \
            atomicAdd(&rowp_[2 * j],     (d_ << 16) >> 16);            \
            atomicAdd(&rowp_[2 * j + 1], d_ >> 16);                    \
        }                                                              \
    }

__global__ __launch_bounds__(256, 4) void fused1_kernel(
    const int4* __restrict__ y4, const short* __restrict__ yh,
    const unsigned int* __restrict__ csr, const int* __restrict__ bcur,
    const float* __restrict__ dinv, const uint4* __restrict__ Wpk,
    const float* __restrict__ b1, const float* __restrict__ v,
    float* __restrict__ zz, int n) {
    __shared__ int acci[BNODES * RSTRIDE];   // 36864 B -> 4 blocks/CU
    int t = threadIdx.x;
    int lane = t & 63, wave = t >> 6;
    int q = lane >> 3, col = lane & 7;
    int b = blockIdx.x;
    int node0 = b << BSHIFT;
    int nlocal = min(BNODES, n - node0);
    int base = b * SCAP;
    int cnt = bcur[b];

    // self-loop init: acc[r][f] = y[node0+r][f] (int16, already dinv-prescaled)
    for (int r = wave; r < BNODES; r += 4) {
        int vv = 0;
        if (r < nlocal) vv = (int)yh[(node0 + r) * 64 + lane];
        acci[r * RSTRIDE + q * 9 + col] = vv;
    }
    __syncthreads();

    // Edge accumulation in tile order: per round each wave owns 64 edges.
    int nr = (cnt + 255) >> 8;
    int lpos = wave * 64 + lane;
    unsigned int ee = (lpos < cnt) ? csr[base + lpos] : SENTE;
    for (int r = 0; r < nr; ++r) {
        int pn = lpos + (r + 1) * 256;
        unsigned int een = (pn < cnt) ? csr[base + pn] : SENTE;
        int4 u[8]; int dl[8];
        F1_ISSUE(ee, u, dl);
        __builtin_amdgcn_sched_barrier(0);   // loads stay above: 8 in flight
        F1_CONSUME(u, dl);
        ee = een;
        __syncthreads();                     // waves stay tile-synced
    }
    __syncthreads();

    // MFMA + epilogue: each wave handles 2 sub-tiles of 16 nodes.
    int mm = lane & 15, kq = lane >> 4;
    for (int i = 0; i < 2; ++i) {
        int st = wave * 2 + i;
        int row = st * 16 + mm;
        float dis = ((row < nlocal) ? dinv[node0 + row] : 0.f) * YINV;
        const int* ap = &acci[row * RSTRIDE];
        half8 A0, A1;
        #pragma unroll
        for (int j = 0; j < 8; ++j) {
            A0[j] = (_Float16)(dis * (float)ap[kq * 9 + j]);
            A1[j] = (_Float16)(dis * (float)ap[(4 + kq) * 9 + j]);
        }
        f32x4 acc[8];
        #pragma unroll
        for (int cb = 0; cb < 8; ++cb) acc[cb] = (f32x4){0.f, 0.f, 0.f, 0.f};
        #pragma unroll
        for (int cb = 0; cb < 8; ++cb) {
            half8 bh0 = as_half8(Wpk[(cb * 2 + 0) * 64 + lane]);
            half8 bh1 = as_half8(Wpk[(cb * 2 + 1) * 64 + lane]);
            half8 bl0 = as_half8(Wpk[1024 + (cb * 2 + 0) * 64 + lane]);
            half8 bl1 = as_half8(Wpk[1024 + (cb * 2 + 1) * 64 + lane]);
            acc[cb] = __builtin_amdgcn_mfma_f32_16x16x32_f16(A0, bh0, acc[cb], 0, 0, 0);
            acc[cb] = __builtin_amdgcn_mfma_f32_16x16x32_f16(A1, bh1, acc[cb], 0, 0, 0);
            acc[cb] = __builtin_amdgcn_mfma_f32_16x16x32_f16(A0, bl0, acc[cb], 0, 0, 0);
            acc[cb] = __builtin_amdgcn_mfma_f32_16x16x32_f16(A1, bl1, acc[cb], 0, 0, 0);
        }
        float zp[4] = {0.f, 0.f, 0.f, 0.f};
        #pragma unroll
        for (int cb = 0; cb < 8; ++cb) {
            int colg = cb * 16 + mm;
            float bb1 = b1[colg], vv = v[colg];
            #pragma unroll
            for (int rr = 0; rr < 4; ++rr) {
                float h = acc[cb][rr] + bb1;
                h = fmaxf(h, 0.f);
                zp[rr] += h * vv;
            }
        }
        #pragma unroll
        for (int off = 1; off < 16; off <<= 1) {
            #pragma unroll
            for (int rr = 0; rr < 4; ++rr) zp[rr] += __shfl_xor(zp[rr], off, 64);
        }
        if (mm == 0) {
            int nb = st * 16 + kq * 4;
            #pragma unroll
            for (int rr = 0; rr < 4; ++rr)
                if (nb + rr < nlocal)
                    zz[node0 + nb + rr] = dinv[node0 + nb + rr] * zp[rr];
        }
    }
}

// Layer 2 (collapsed): per-bucket tile-major zz gather (L1/L2 window) +
// native int LDS accumulate. out[i] = c + dinv[i]*(zz[i] + sum_in zz[s]).
__global__ __launch_bounds__(256) void out_kernel(
    const int* __restrict__ bcur, const unsigned int* __restrict__ csr,
    const float* __restrict__ dinv, const float* __restrict__ zz,
    const float* __restrict__ c, float* __restrict__ out, int n) {
    __shared__ int acc2[BNODES];
    int b = blockIdx.x, t = threadIdx.x;
    int node0 = b << BSHIFT;
    int nlocal = min(BNODES, n - node0);
    int base = b * SCAP;
    int cnt = bcur[b];
    if (t < BNODES) acc2[t] = 0;
    __syncthreads();
    for (int idx = t; idx < cnt; idx += 256) {
        unsigned int e = csr[base + idx];
        float z = zz[e >> BSHIFT];
        atomicAdd(&acc2[e & (BNODES - 1)], __float2int_rn(z * ZSCALE));
    }
    __syncthreads();
    if (t < nlocal) {
        int node = node0 + t;
        out[node] = c[0] + dinv[node] * ((float)acc2[t] * ZINV + zz[node]);
    }
}

extern "C" void kernel_launch(void* const* d_in, const int* in_sizes, int n_in,
                              void* d_out, int out_size, void* d_ws, size_t ws_size,
                              hipStream_t stream) {
    const float* x  = (const float*)d_in[0];
    const int*   ei = (const int*)d_in[1];
    const float* W1 = (const float*)d_in[2];
    const float* b1 = (const float*)d_in[3];
    const float* W2 = (const float*)d_in[4];
    const float* b2 = (const float*)d_in[5];
    const float* Wl = (const float*)d_in[6];
    const float* bl = (const float*)d_in[7];
    float* out = (float*)d_out;

    int E = in_sizes[1] / 2;
    const int* src = ei;
    const int* dst = ei + E;

    float* ws      = (float*)d_ws;
    float* dinv    = ws;                        // 100000
    float* zz      = dinv + N_NODES;            // 100000
    float* v       = zz + N_NODES;              // 128
    float* c       = v + HID;                   // 4
    int*   bcur    = (int*)(c + 4);             // 782 counts (pad to 1024)
    int*   csr     = bcur + NB_PAD;             // NBUCKETS*SCAP = 2001920 ints
    uint4* Wpk     = (uint4*)(csr + (size_t)NBUCKETS * SCAP);  // 2048 uint4
    short* y       = (short*)((float*)Wpk + 8192);  // (N+4)*64 int16

    int nchunks = (E + ACHUNK - 1) / ACHUNK;   // 391

    hipMemsetAsync(bcur, 0, NBUCKETS * sizeof(int), stream);
    partA_kernel<<<nchunks + 9, 256, 0, stream>>>(
        src, dst, bcur, (unsigned int*)csr, E, nchunks,
        W1, W2, b2, Wl, bl, v, c, Wpk, (int*)(y + (size_t)ZROW * 64));
    partB_kernel<<<NBUCKETS, 256, 0, stream>>>(
        bcur, (unsigned int*)csr, dinv, (const float4*)x, (uint2*)y, N_NODES);
    fused1_kernel<<<NBUCKETS, 256, 0, stream>>>(
        (const int4*)y, (const short*)y, (const unsigned int*)csr,
        bcur, dinv, Wpk, b1, v, zz, N_NODES);
    out_kernel<<<NBUCKETS, 256, 0, stream>>>(
        bcur, (const unsigned int*)csr, dinv, zz, c, out, N_NODES);
}